// Round 6
// baseline (135.471 us; speedup 1.0000x reference)
//
#include <hip/hip_runtime.h>
#include <hip/hip_bf16.h>
#include <stdint.h>

typedef __attribute__((ext_vector_type(8))) __bf16 bf16x8;
typedef __attribute__((ext_vector_type(4))) float f32x4;
typedef __attribute__((ext_vector_type(4))) int   i32x4;
typedef __attribute__((ext_vector_type(4))) uint32_t u32x4;

#define B_SZ 8
#define E_SZ 8192
#define T_SZ 2048
#define D_SZ 256
#define H_SZ 256
#define NP   768      // interleaved i,g,o columns

#define BM 128
#define BN 192
#define BK 64
#define KT 4
#define NTHR 512
#define NWG  2048     // (65536/BM) * (768/BN)
#define TILE_BYTES ((BM + BN) * BK * 2)   // 40960

#define NODE_H_OFF 0
#define NODE_C_OFF (B_SZ*T_SZ*H_SZ)                       // 4194304
#define EDGE_H_OFF (2*B_SZ*T_SZ*H_SZ)                     // 8388608
#define EDGE_C_OFF (2*B_SZ*T_SZ*H_SZ + B_SZ*E_SZ*H_SZ)    // 25165824

__device__ __forceinline__ uint32_t pk_bf16(float a, float b) {
    uint32_t ua = __float_as_uint(a);
    uint32_t ub = __float_as_uint(b);
    ua += 0x7fffu + ((ua >> 16) & 1u);   // RNE
    ub += 0x7fffu + ((ub >> 16) & 1u);
    return (ua >> 16) | (ub & 0xffff0000u);
}

// weight_ih [256][1024] f32 -> Wt [768][256] bf16 (transposed, gate-interleaved:
// n' = 48*t + 16*s + u  <->  original col gate_off(s) + 16*t + u, s in {i,g,o})
// f-gate columns dropped (c0 == 0). bias similarly permuted into biasp[768].
__global__ void wcvt_kernel(const float* __restrict__ W, const float* __restrict__ bias,
                            uint16_t* __restrict__ Wt, float* __restrict__ biasp) {
    int id = blockIdx.x * 256 + threadIdx.x;
    if (id < 256 * 768) {
        int k = id / 768;
        int q = id - k * 768;                 // q in [0,768): 0-255 i, 256-511 g, 512-767 o
        int col = (q < 256) ? q : (q + 256);  // skip f chunk [256,512)
        int s = q >> 8;
        int j = q & 255;
        int np = 48 * (j >> 4) + 16 * s + (j & 15);
        uint32_t ua = __float_as_uint(W[k * 1024 + col]);
        ua += 0x7fffu + ((ua >> 16) & 1u);
        Wt[np * 256 + k] = (uint16_t)(ua >> 16);
        if (k == 0) biasp[np] = bias[col];
    }
}

// GEMM [65536 x 256] (f32->bf16 inline) @ Wt^T [256 x 768] + fused activations.
// R3 structure (128x192, BK=64, dbuf, 24 MFMA/phase) + T4 counted-vmcnt:
// per iter, issue order pinned [B(t+1) gload_lds][A(t+2) reg loads], compute(t),
// pack A(t+1) (counted wait keeps B+A(t+2) in flight), lgkm(0), vmcnt(4),
// raw s_barrier. No vmcnt(0) drain in the loop; A gets 2 iters of latency cover.
__launch_bounds__(NTHR, 4)
__global__ void gemm_act_kernel(const float* __restrict__ A,
                                const uint16_t* __restrict__ Wt,
                                const float* __restrict__ biasp,
                                float* __restrict__ out) {
    __shared__ __align__(16) char smem[2 * TILE_BYTES];

    const int tid  = threadIdx.x;
    // XCD-aware bijective swizzle (NWG % 8 == 0)
    const int bid  = blockIdx.x;
    const int wg   = (bid & 7) * (NWG / 8) + (bid >> 3);
    const int mb   = wg >> 2;         // 0..511
    const int nb   = wg & 3;          // 0..3
    const int m0   = mb * BM;
    const int n0   = nb * BN;

    const int wid  = tid >> 6;
    const int lane = tid & 63;
    const int wm   = wid >> 2;        // 0..1
    const int wn   = wid & 3;         // 0..3
    const int l15  = lane & 15;
    const int lq   = lane >> 4;

    // A staging geometry (2 chunks of 8 f32 per thread per k-tile)
    const int aid0  = tid;
    const int aid1  = NTHR + tid;
    const int arow0 = aid0 >> 3, ac0 = (aid0 & 7) * 16;   // byte col in 128-B bf16 row
    const int arow1 = aid1 >> 3, ac1 = (aid1 & 7) * 16;
    const int asw0  = ac0 ^ ((arow0 & 7) << 4);
    const int asw1  = ac1 ^ ((arow1 & 7) << 4);
    const float* ga0base = A + (size_t)(m0 + arow0) * D_SZ + (ac0 >> 1);
    const float* ga1base = A + (size_t)(m0 + arow1) * D_SZ + (ac1 >> 1);

    // xs[slot][chunk][half]: A-tile stage s lives in slot s&1. All indices
    // compile-time after full unroll (rule #20: no runtime indexing).
    f32x4 xs[2][2][2];

    // ---- prologue: A(0), B(0), A(1) in pinned issue order
    xs[0][0][0] = *(const f32x4*)(ga0base);
    xs[0][0][1] = *(const f32x4*)(ga0base + 4);
    xs[0][1][0] = *(const f32x4*)(ga1base);
    xs[0][1][1] = *(const f32x4*)(ga1base + 4);
    __builtin_amdgcn_sched_barrier(0);
    #pragma unroll
    for (int r2 = 0; r2 < 3; ++r2) {
        int p   = (r2 * NTHR + tid) * 16;
        int row = p >> 7;
        int csw = (p & 127) ^ ((row & 7) << 4);
        const uint16_t* g = Wt + (n0 + row) * 256 + (csw >> 1);
        __builtin_amdgcn_global_load_lds(
            (const __attribute__((address_space(1))) uint32_t*)g,
            (__attribute__((address_space(3))) uint32_t*)(smem + BM * BK * 2 + p), 16, 0, 0);
    }
    __builtin_amdgcn_sched_barrier(0);
    xs[1][0][0] = *(const f32x4*)(ga0base + BK);
    xs[1][0][1] = *(const f32x4*)(ga0base + BK + 4);
    xs[1][1][0] = *(const f32x4*)(ga1base + BK);
    xs[1][1][1] = *(const f32x4*)(ga1base + BK + 4);
    __builtin_amdgcn_sched_barrier(0);
    {   // pack A(0) -> buf0 (compiler emits counted vmcnt: drains A(0) only)
        u32x4 v0 = { pk_bf16(xs[0][0][0].x,xs[0][0][0].y), pk_bf16(xs[0][0][0].z,xs[0][0][0].w),
                     pk_bf16(xs[0][0][1].x,xs[0][0][1].y), pk_bf16(xs[0][0][1].z,xs[0][0][1].w) };
        u32x4 v1 = { pk_bf16(xs[0][1][0].x,xs[0][1][0].y), pk_bf16(xs[0][1][0].z,xs[0][1][0].w),
                     pk_bf16(xs[0][1][1].x,xs[0][1][1].y), pk_bf16(xs[0][1][1].z,xs[0][1][1].w) };
        *(u32x4*)(smem + arow0 * 128 + asw0) = v0;
        *(u32x4*)(smem + arow1 * 128 + asw1) = v1;
    }
    asm volatile("s_waitcnt lgkmcnt(0)" ::: "memory");
    asm volatile("s_waitcnt vmcnt(4)" ::: "memory");   // drain B(0); A(1) stays in flight
    __builtin_amdgcn_s_barrier();

    f32x4 acc[4][3];
    #pragma unroll
    for (int mf = 0; mf < 4; ++mf)
        #pragma unroll
        for (int nf = 0; nf < 3; ++nf)
            acc[mf][nf] = (f32x4){0.f, 0.f, 0.f, 0.f};

    #pragma unroll
    for (int kt = 0; kt < KT; ++kt) {
        char* AsC = smem + (kt & 1) * TILE_BYTES;
        char* BsC = AsC + BM * BK * 2;
        char* AsN = smem + ((kt + 1) & 1) * TILE_BYTES;
        char* BsN = AsN + BM * BK * 2;

        // ---- issue B(kt+1) gload_lds (oldest in queue)
        if (kt < KT - 1) {
            const int k0n = (kt + 1) * BK;
            #pragma unroll
            for (int r2 = 0; r2 < 3; ++r2) {
                int p   = (r2 * NTHR + tid) * 16;
                int row = p >> 7;
                int csw = (p & 127) ^ ((row & 7) << 4);
                const uint16_t* g = Wt + (n0 + row) * 256 + k0n + (csw >> 1);
                __builtin_amdgcn_global_load_lds(
                    (const __attribute__((address_space(1))) uint32_t*)g,
                    (__attribute__((address_space(3))) uint32_t*)(BsN + p), 16, 0, 0);
            }
        }
        __builtin_amdgcn_sched_barrier(0);
        // ---- issue A(kt+2) reg loads (newest; cross the barrier in regs)
        if (kt < KT - 2) {
            const int k0n2 = (kt + 2) * BK;
            xs[kt & 1][0][0] = *(const f32x4*)(ga0base + k0n2);
            xs[kt & 1][0][1] = *(const f32x4*)(ga0base + k0n2 + 4);
            xs[kt & 1][1][0] = *(const f32x4*)(ga1base + k0n2);
            xs[kt & 1][1][1] = *(const f32x4*)(ga1base + k0n2 + 4);
        }
        __builtin_amdgcn_sched_barrier(0);

        // ---- compute tile kt: 2 kk x (4 A-frags, 3 B-frags) -> 24 MFMA
        #pragma unroll
        for (int kk = 0; kk < 2; ++kk) {
            const int kb = kk * 64 + lq * 16;
            bf16x8 af[4], bfr[3];
            #pragma unroll
            for (int mf = 0; mf < 4; ++mf) {
                int row = wm * 64 + mf * 16 + l15;
                af[mf] = *(const bf16x8*)(AsC + row * 128 + (kb ^ ((row & 7) << 4)));
            }
            #pragma unroll
            for (int nf = 0; nf < 3; ++nf) {
                int row = wn * 48 + nf * 16 + l15;
                bfr[nf] = *(const bf16x8*)(BsC + row * 128 + (kb ^ ((row & 7) << 4)));
            }
            #pragma unroll
            for (int mf = 0; mf < 4; ++mf)
                #pragma unroll
                for (int nf = 0; nf < 3; ++nf)
                    acc[mf][nf] = __builtin_amdgcn_mfma_f32_16x16x32_bf16(
                        af[mf], bfr[nf], acc[mf][nf], 0, 0, 0);
        }

        // ---- pack A(kt+1) (auto counted wait), lgkm drain, counted vmcnt, barrier
        if (kt < KT - 1) {
            const int sl = (kt + 1) & 1;
            u32x4 v0 = { pk_bf16(xs[sl][0][0].x,xs[sl][0][0].y), pk_bf16(xs[sl][0][0].z,xs[sl][0][0].w),
                         pk_bf16(xs[sl][0][1].x,xs[sl][0][1].y), pk_bf16(xs[sl][0][1].z,xs[sl][0][1].w) };
            u32x4 v1 = { pk_bf16(xs[sl][1][0].x,xs[sl][1][0].y), pk_bf16(xs[sl][1][0].z,xs[sl][1][0].w),
                         pk_bf16(xs[sl][1][1].x,xs[sl][1][1].y), pk_bf16(xs[sl][1][1].z,xs[sl][1][1].w) };
            *(u32x4*)(AsN + arow0 * 128 + asw0) = v0;
            *(u32x4*)(AsN + arow1 * 128 + asw1) = v1;
            asm volatile("s_waitcnt lgkmcnt(0)" ::: "memory");
            if (kt < KT - 2) {
                asm volatile("s_waitcnt vmcnt(4)" ::: "memory");  // drain B(kt+1); keep A(kt+2)
            } else {
                asm volatile("s_waitcnt vmcnt(0)" ::: "memory");  // tail: nothing to keep
            }
            __builtin_amdgcn_s_barrier();
        }
    }

    // --- fused epilogue: c = sig(i)*tanh(g), h = sig(o)*tanh(o) = (1-e^-o)/(1+e^-2o)
    const float L2E = 1.44269504088896340736f;
    const int jj = (nb * 4 + wn) * 16 + l15;              // hidden index 0..255
    const int bb = n0 + wn * 48 + l15;
    const float bi = biasp[bb];
    const float bg = biasp[bb + 16];
    const float bo = biasp[bb + 32];
    float* __restrict__ eh = out + EDGE_H_OFF;
    float* __restrict__ ec = out + EDGE_C_OFF;
    #pragma unroll
    for (int mf = 0; mf < 4; ++mf) {
        const int mbase = m0 + wm * 64 + mf * 16 + lq * 4;
        #pragma unroll
        for (int r = 0; r < 4; ++r) {
            const size_t m = (size_t)(mbase + r);
            float pi = acc[mf][0][r] + bi;
            float pg = acc[mf][1][r] + bg;
            float po = acc[mf][2][r] + bo;
            float ei = __builtin_amdgcn_exp2f(-L2E * pi);          // e^-i
            float eg = __builtin_amdgcn_exp2f(-2.f * L2E * pg);    // e^-2g
            float eo = __builtin_amdgcn_exp2f(-L2E * po);          // e^-o
            float c  = (1.f - eg) * __builtin_amdgcn_rcpf((1.f + ei) * (1.f + eg));
            float h  = (1.f - eo) * __builtin_amdgcn_rcpf(1.f + eo * eo);
            eh[m * H_SZ + jj] = h;
            ec[m * H_SZ + jj] = c;
        }
    }
}

// node_{h,c}[b,t,:] = mean over k of edge_{h,c}[b, prev[t,k], :]
// one wave per (b,t) pair; float4 per lane covers the 256-wide row.
__global__ void node_mean_kernel(const int* __restrict__ prev,
                                 const float* __restrict__ outr,
                                 float* __restrict__ out) {
    int gid  = blockIdx.x * 4 + (threadIdx.x >> 6);       // 0..16383
    int lane = threadIdx.x & 63;
    int b = gid >> 11;
    int t = gid & 2047;
    const float* eh = outr + EDGE_H_OFF + (size_t)b * E_SZ * H_SZ;
    const float* ec = outr + EDGE_C_OFF + (size_t)b * E_SZ * H_SZ;
    i32x4 e4 = *(const i32x4*)(prev + t * 4);
    f32x4 hs = (f32x4){0.f,0.f,0.f,0.f};
    f32x4 cs = (f32x4){0.f,0.f,0.f,0.f};
    #pragma unroll
    for (int k = 0; k < 4; ++k) {
        size_t off = (size_t)e4[k] * H_SZ + lane * 4;
        hs += *(const f32x4*)(eh + off);
        cs += *(const f32x4*)(ec + off);
    }
    hs *= 0.25f; cs *= 0.25f;
    size_t o = (size_t)(b * T_SZ + t) * H_SZ + lane * 4;
    *(f32x4*)(out + NODE_H_OFF + o) = hs;
    *(f32x4*)(out + NODE_C_OFF + o) = cs;
}

extern "C" void kernel_launch(void* const* d_in, const int* in_sizes, int n_in,
                              void* d_out, int out_size, void* d_ws, size_t ws_size,
                              hipStream_t stream) {
    const float* edge_input = (const float*)d_in[0];
    const float* weight_ih  = (const float*)d_in[1];
    // d_in[2] = weight_hh: mathematically dead (node_h read before write => 0)
    const float* bias       = (const float*)d_in[3];
    const int*   prev_idx   = (const int*)d_in[4];
    float* out = (float*)d_out;

    uint16_t* Wt    = (uint16_t*)d_ws;                    // 768*256*2 = 384 KiB
    float*    biasp = (float*)((char*)d_ws + NP * 256 * 2);

    wcvt_kernel<<<(256 * 768 + 255) / 256, 256, 0, stream>>>(weight_ih, bias, Wt, biasp);
    gemm_act_kernel<<<NWG, NTHR, 0, stream>>>(edge_input, Wt, biasp, out);
    node_mean_kernel<<<(B_SZ * T_SZ) / 4, 256, 0, stream>>>(prev_idx, out, out);
}

// Round 7
// 77.719 us; speedup vs baseline: 1.7431x; 1.7431x over previous
//
#include <hip/hip_runtime.h>
#include <hip/hip_bf16.h>
#include <stdint.h>

typedef __attribute__((ext_vector_type(8))) __bf16 bf16x8;
typedef __attribute__((ext_vector_type(4))) float f32x4;
typedef __attribute__((ext_vector_type(4))) int   i32x4;
typedef __attribute__((ext_vector_type(4))) uint32_t u32x4;

#define B_SZ 8
#define E_SZ 8192
#define T_SZ 2048
#define D_SZ 256
#define H_SZ 256
#define NP   768      // interleaved i,g,o columns

#define BM 128
#define BN 192
#define BK 64
#define NTHR 512
#define NWG  2048     // (65536/BM) * (768/BN)
#define TILE_BYTES ((BM + BN) * BK * 2)   // 40960

#define NODE_H_OFF 0
#define NODE_C_OFF (B_SZ*T_SZ*H_SZ)                       // 4194304
#define EDGE_H_OFF (2*B_SZ*T_SZ*H_SZ)                     // 8388608
#define EDGE_C_OFF (2*B_SZ*T_SZ*H_SZ + B_SZ*E_SZ*H_SZ)    // 25165824

__device__ __forceinline__ uint32_t pk_bf16(float a, float b) {
    uint32_t ua = __float_as_uint(a);
    uint32_t ub = __float_as_uint(b);
    ua += 0x7fffu + ((ua >> 16) & 1u);   // RNE
    ub += 0x7fffu + ((ub >> 16) & 1u);
    return (ua >> 16) | (ub & 0xffff0000u);
}

// weight_ih [256][1024] f32 -> Wt [768][256] bf16 (transposed, gate-interleaved:
// n' = 48*t + 16*s + u  <->  original col gate_off(s) + 16*t + u, s in {i,g,o})
// f-gate columns dropped (c0 == 0). bias similarly permuted into biasp[768].
__global__ void wcvt_kernel(const float* __restrict__ W, const float* __restrict__ bias,
                            uint16_t* __restrict__ Wt, float* __restrict__ biasp) {
    int id = blockIdx.x * 256 + threadIdx.x;
    if (id < 256 * 768) {
        int k = id / 768;
        int q = id - k * 768;                 // q in [0,768): 0-255 i, 256-511 g, 512-767 o
        int col = (q < 256) ? q : (q + 256);  // skip f chunk [256,512)
        int s = q >> 8;
        int j = q & 255;
        int np = 48 * (j >> 4) + 16 * s + (j & 15);
        uint32_t ua = __float_as_uint(W[k * 1024 + col]);
        ua += 0x7fffu + ((ua >> 16) & 1u);
        Wt[np * 256 + k] = (uint16_t)(ua >> 16);
        if (k == 0) biasp[np] = bias[col];
    }
}

// GEMM [65536 x 256] (f32->bf16 inline) @ Wt^T [256 x 768] + fused activations.
// R3-exact structure (best measured): 128x192 tile, BK=64, 8 waves (2Mx4N),
// double-buffered LDS, stage(t+1) issued before compute(t), one barrier/iter.
// Two later restructures (B-panel-once, counted-vmcnt 2-deep prefetch) both
// regressed (latency exposure / VGPR spills) — do not touch this loop.
__launch_bounds__(NTHR, 4)
__global__ void gemm_act_kernel(const float* __restrict__ A,
                                const uint16_t* __restrict__ Wt,
                                const float* __restrict__ biasp,
                                float* __restrict__ out) {
    __shared__ __align__(16) char smem[2 * TILE_BYTES];

    const int tid  = threadIdx.x;
    // XCD-aware bijective swizzle (NWG % 8 == 0)
    const int bid  = blockIdx.x;
    const int wg   = (bid & 7) * (NWG / 8) + (bid >> 3);
    const int mb   = wg >> 2;         // 0..511
    const int nb   = wg & 3;          // 0..3
    const int m0   = mb * BM;
    const int n0   = nb * BN;

    const int wid  = tid >> 6;
    const int lane = tid & 63;
    const int wm   = wid >> 2;        // 0..1
    const int wn   = wid & 3;         // 0..3
    const int l15  = lane & 15;
    const int lq   = lane >> 4;

    // Per-thread staging geometry (constant across iters)
    const int aid0  = tid;                   // A chunk ids
    const int aid1  = NTHR + tid;
    const int arow0 = aid0 >> 3, ac0 = (aid0 & 7) * 16;  // byte col of 8-elem chunk
    const int arow1 = aid1 >> 3, ac1 = (aid1 & 7) * 16;
    const int asw0  = ac0 ^ ((arow0 & 7) << 4);
    const int asw1  = ac1 ^ ((arow1 & 7) << 4);

    f32x4 acc[4][3];
    #pragma unroll
    for (int mf = 0; mf < 4; ++mf)
        #pragma unroll
        for (int nf = 0; nf < 3; ++nf)
            acc[mf][nf] = (f32x4){0.f, 0.f, 0.f, 0.f};

    // ---- prologue: stage tile 0 into buffer 0
    {
        char* As = smem;
        char* Bs = smem + BM * BK * 2;
        const float* ga0 = A + (size_t)(m0 + arow0) * D_SZ + (ac0 >> 1);
        const float* ga1 = A + (size_t)(m0 + arow1) * D_SZ + (ac1 >> 1);
        f32x4 x0 = *(const f32x4*)ga0, x1 = *(const f32x4*)(ga0 + 4);
        f32x4 x2 = *(const f32x4*)ga1, x3 = *(const f32x4*)(ga1 + 4);
        #pragma unroll
        for (int r2 = 0; r2 < 3; ++r2) {
            int p   = (r2 * NTHR + tid) * 16;
            int row = p >> 7;
            int csw = (p & 127) ^ ((row & 7) << 4);
            const uint16_t* g = Wt + (n0 + row) * 256 + (csw >> 1);
            __builtin_amdgcn_global_load_lds(
                (const __attribute__((address_space(1))) uint32_t*)g,
                (__attribute__((address_space(3))) uint32_t*)(Bs + p), 16, 0, 0);
        }
        u32x4 v0 = { pk_bf16(x0.x,x0.y), pk_bf16(x0.z,x0.w), pk_bf16(x1.x,x1.y), pk_bf16(x1.z,x1.w) };
        u32x4 v1 = { pk_bf16(x2.x,x2.y), pk_bf16(x2.z,x2.w), pk_bf16(x3.x,x3.y), pk_bf16(x3.z,x3.w) };
        *(u32x4*)(As + arow0 * 128 + asw0) = v0;
        *(u32x4*)(As + arow1 * 128 + asw1) = v1;
    }
    __syncthreads();

    #pragma unroll
    for (int kt = 0; kt < 4; ++kt) {
        char* AsC = smem + (kt & 1) * TILE_BYTES;
        char* BsC = AsC + BM * BK * 2;
        char* AsN = smem + ((kt + 1) & 1) * TILE_BYTES;
        char* BsN = AsN + BM * BK * 2;

        // ---- stage tile kt+1: A global loads first (reg), then B gload_lds.
        f32x4 x0, x1, x2, x3;
        if (kt < 3) {
            const int k0n = (kt + 1) * BK;
            const float* ga0 = A + (size_t)(m0 + arow0) * D_SZ + k0n + (ac0 >> 1);
            const float* ga1 = A + (size_t)(m0 + arow1) * D_SZ + k0n + (ac1 >> 1);
            x0 = *(const f32x4*)ga0; x1 = *(const f32x4*)(ga0 + 4);
            x2 = *(const f32x4*)ga1; x3 = *(const f32x4*)(ga1 + 4);
            #pragma unroll
            for (int r2 = 0; r2 < 3; ++r2) {
                int p   = (r2 * NTHR + tid) * 16;
                int row = p >> 7;
                int csw = (p & 127) ^ ((row & 7) << 4);
                const uint16_t* g = Wt + (n0 + row) * 256 + k0n + (csw >> 1);
                __builtin_amdgcn_global_load_lds(
                    (const __attribute__((address_space(1))) uint32_t*)g,
                    (__attribute__((address_space(3))) uint32_t*)(BsN + p), 16, 0, 0);
            }
        }

        // ---- compute on current buffer: 2 k-frags x (4 A, 3 B) -> 24 MFMA
        #pragma unroll
        for (int kk = 0; kk < 2; ++kk) {
            const int kb = kk * 64 + lq * 16;
            bf16x8 af[4], bfr[3];
            #pragma unroll
            for (int mf = 0; mf < 4; ++mf) {
                int row = wm * 64 + mf * 16 + l15;
                af[mf] = *(const bf16x8*)(AsC + row * 128 + (kb ^ ((row & 7) << 4)));
            }
            #pragma unroll
            for (int nf = 0; nf < 3; ++nf) {
                int row = wn * 48 + nf * 16 + l15;
                bfr[nf] = *(const bf16x8*)(BsC + row * 128 + (kb ^ ((row & 7) << 4)));
            }
            #pragma unroll
            for (int mf = 0; mf < 4; ++mf)
                #pragma unroll
                for (int nf = 0; nf < 3; ++nf)
                    acc[mf][nf] = __builtin_amdgcn_mfma_f32_16x16x32_bf16(
                        af[mf], bfr[nf], acc[mf][nf], 0, 0, 0);
        }

        // ---- write-late: pack A (waits only A loads; B gload_lds stays in flight)
        if (kt < 3) {
            u32x4 v0 = { pk_bf16(x0.x,x0.y), pk_bf16(x0.z,x0.w), pk_bf16(x1.x,x1.y), pk_bf16(x1.z,x1.w) };
            u32x4 v1 = { pk_bf16(x2.x,x2.y), pk_bf16(x2.z,x2.w), pk_bf16(x3.x,x3.y), pk_bf16(x3.z,x3.w) };
            *(u32x4*)(AsN + arow0 * 128 + asw0) = v0;
            *(u32x4*)(AsN + arow1 * 128 + asw1) = v1;
            __syncthreads();
        }
    }

    // --- fused epilogue: c = sig(i)*tanh(g), h = sig(o)*tanh(o) = (1-e^-o)/(1+e^-2o)
    const float L2E = 1.44269504088896340736f;
    const int jj = (nb * 4 + wn) * 16 + l15;              // hidden index 0..255
    const int bb = n0 + wn * 48 + l15;
    const float bi = biasp[bb];
    const float bg = biasp[bb + 16];
    const float bo = biasp[bb + 32];
    float* __restrict__ eh = out + EDGE_H_OFF;
    float* __restrict__ ec = out + EDGE_C_OFF;
    #pragma unroll
    for (int mf = 0; mf < 4; ++mf) {
        const int mbase = m0 + wm * 64 + mf * 16 + lq * 4;
        #pragma unroll
        for (int r = 0; r < 4; ++r) {
            const size_t m = (size_t)(mbase + r);
            float pi = acc[mf][0][r] + bi;
            float pg = acc[mf][1][r] + bg;
            float po = acc[mf][2][r] + bo;
            float ei = __builtin_amdgcn_exp2f(-L2E * pi);          // e^-i
            float eg = __builtin_amdgcn_exp2f(-2.f * L2E * pg);    // e^-2g
            float eo = __builtin_amdgcn_exp2f(-L2E * po);          // e^-o
            float c  = (1.f - eg) * __builtin_amdgcn_rcpf((1.f + ei) * (1.f + eg));
            float h  = (1.f - eo) * __builtin_amdgcn_rcpf(1.f + eo * eo);
            eh[m * H_SZ + jj] = h;
            ec[m * H_SZ + jj] = c;
        }
    }
}

// node_{h,c}[b,t,:] = mean over k of edge_{h,c}[b, prev[t,k], :]
// v2: TWO wave-tasks per (b,t) — one for h, one for c. 32768 waves total,
// 4 gather loads + 1 store each: 2x task parallelism for latency hiding.
__global__ void node_mean_kernel(const int* __restrict__ prev,
                                 const float* __restrict__ outr,
                                 float* __restrict__ out) {
    int gid  = blockIdx.x * 4 + (threadIdx.x >> 6);       // 0..32767
    int lane = threadIdx.x & 63;
    int half = gid & 1;                                   // 0: h, 1: c
    int pair = gid >> 1;                                  // 0..16383
    int b = pair >> 11;
    int t = pair & 2047;
    const float* src = outr + (half ? EDGE_C_OFF : EDGE_H_OFF)
                            + (size_t)b * E_SZ * H_SZ;
    i32x4 e4 = *(const i32x4*)(prev + t * 4);
    f32x4 s = (f32x4){0.f,0.f,0.f,0.f};
    #pragma unroll
    for (int k = 0; k < 4; ++k) {
        s += *(const f32x4*)(src + (size_t)e4[k] * H_SZ + lane * 4);
    }
    s *= 0.25f;
    size_t o = (half ? NODE_C_OFF : NODE_H_OFF)
             + (size_t)(b * T_SZ + t) * H_SZ + lane * 4;
    *(f32x4*)(out + o) = s;
}

extern "C" void kernel_launch(void* const* d_in, const int* in_sizes, int n_in,
                              void* d_out, int out_size, void* d_ws, size_t ws_size,
                              hipStream_t stream) {
    const float* edge_input = (const float*)d_in[0];
    const float* weight_ih  = (const float*)d_in[1];
    // d_in[2] = weight_hh: mathematically dead (node_h read before write => 0)
    const float* bias       = (const float*)d_in[3];
    const int*   prev_idx   = (const int*)d_in[4];
    float* out = (float*)d_out;

    uint16_t* Wt    = (uint16_t*)d_ws;                    // 768*256*2 = 384 KiB
    float*    biasp = (float*)((char*)d_ws + NP * 256 * 2);

    wcvt_kernel<<<(256 * 768 + 255) / 256, 256, 0, stream>>>(weight_ih, bias, Wt, biasp);
    gemm_act_kernel<<<NWG, NTHR, 0, stream>>>(edge_input, Wt, biasp, out);
    node_mean_kernel<<<(2 * B_SZ * T_SZ) / 4, 256, 0, stream>>>(prev_idx, out, out);
}